// Round 4
// baseline (312.626 us; speedup 1.0000x reference)
//
#include <hip/hip_runtime.h>

#define NN 1024
#define DD 256
#define HH 32
#define SS 64

typedef short bf16x8 __attribute__((ext_vector_type(8)));
typedef float f32x4  __attribute__((ext_vector_type(4)));

__device__ __forceinline__ unsigned short f2bf(float f) {
    union { float f; unsigned int i; } v; v.f = f;
    unsigned int r = v.i + 0x7FFFu + ((v.i >> 16) & 1u);  // RNE; no NaN expected
    return (unsigned short)(r >> 16);
}

__device__ __forceinline__ float gelu_f(float x) {
    // jax.nn.gelu approximate=True
    const float c1 = 0.7978845608028654f, c2 = 0.044715f;
    float u = c1 * fmaf(c2 * x * x, x, x);
    float e = __expf(-2.0f * fabsf(u));
    float th = (1.0f - e) / (1.0f + e);
    th = copysignf(th, u);
    return 0.5f * x * (1.0f + th);
}

// left = local @ W_left, right = local @ W_right  (fp32 out to workspace)
__global__ __launch_bounds__(64) void proj_kernel(
    const float* __restrict__ local_,
    const float* __restrict__ Wl,
    const float* __restrict__ Wr,
    float* __restrict__ leftF, float* __restrict__ rightF)
{
    __shared__ float row[DD];
    const int i = blockIdx.x, t = threadIdx.x;
    float4 v = ((const float4*)(local_ + (size_t)i * DD))[t];
    row[4*t+0] = v.x; row[4*t+1] = v.y; row[4*t+2] = v.z; row[4*t+3] = v.w;
    __syncthreads();
    const int h = t & 31;
    const float* W = (t < 32) ? Wl : Wr;
    float acc = 0.0f;
    #pragma unroll 8
    for (int d = 0; d < DD; ++d) acc = fmaf(row[d], W[d*HH + h], acc);
    float* dst = (t < 32) ? leftF : rightF;
    dst[i*HH + h] = acc;
}

__global__ __launch_bounds__(256) void pair_kernel(
    const float* __restrict__ leftF, const float* __restrict__ rightF,
    const int* __restrict__ resi, const int* __restrict__ chain,
    const int* __restrict__ batch, const int* __restrict__ mask,
    const float* __restrict__ Wrel,
    const float* __restrict__ lnS, const float* __restrict__ lnO,
    const float* __restrict__ Wh, const float* __restrict__ Wout,
    float* __restrict__ out)
{
    __shared__ float relL[65 * 36];              // padded rows: 36 f32 (bank-spread)
    __shared__ unsigned short WhT[32 * 32];      // WhT[n][k] = Wh[k][n], bf16
    __shared__ unsigned short WoT[64 * 32];      // WoT[s][k'] = Wout[perm(k')][s], bf16
    __shared__ unsigned short hidL[4 * 16 * 40]; // per-wave: 16 pairs x 40-short rows

    const int tid  = threadIdx.x;
    const int wave = tid >> 6;
    const int lane = tid & 63;
    const int q    = lane >> 4;    // quad 0..3
    const int p    = lane & 15;    // pair-slot 0..15
    const int i    = blockIdx.y;
    const int jb   = blockIdx.x;   // 0..3, each covers 256 j

    // ---- one-time staging ----
    for (int idx = tid; idx < 65 * 32; idx += 256)
        relL[(idx >> 5) * 36 + (idx & 31)] = Wrel[idx];
    for (int idx = tid; idx < 32 * 32; idx += 256) {
        int k = idx >> 5, n = idx & 31;
        WhT[n * 32 + k] = f2bf(Wh[idx]);
    }
    for (int idx = tid; idx < 64 * 32; idx += 256) {
        int k2 = idx >> 6, s = idx & 63;             // k2 = permuted feature slot
        int k  = (k2 >> 1) + (k2 & 1) * 16;          // hid slot 2p -> col p, 2p+1 -> col p+16
        WoT[s * 32 + k2] = f2bf(Wout[k * SS + s]);
    }
    __syncthreads();

    // ---- block-constant registers ----
    const int bi = batch[i], ci = chain[i], ri = resi[i], mi = mask[i];
    float left8[8], lnS8[8], lnO8[8];
    {
        const float4 l0 = *(const float4*)&leftF[i * HH + 8 * q];
        const float4 l1 = *(const float4*)&leftF[i * HH + 8 * q + 4];
        left8[0]=l0.x; left8[1]=l0.y; left8[2]=l0.z; left8[3]=l0.w;
        left8[4]=l1.x; left8[5]=l1.y; left8[6]=l1.z; left8[7]=l1.w;
        #pragma unroll
        for (int e = 0; e < 8; ++e) { lnS8[e] = lnS[8*q + e]; lnO8[e] = lnO[8*q + e]; }
    }
    const bf16x8 whB0 = *(const bf16x8*)&WhT[(p      ) * 32 + 8 * q];
    const bf16x8 whB1 = *(const bf16x8*)&WhT[(16 + p ) * 32 + 8 * q];
    bf16x8 woB[4];
    #pragma unroll
    for (int t = 0; t < 4; ++t)
        woB[t] = *(const bf16x8*)&WoT[(16 * t + p) * 32 + 8 * q];

    unsigned short* hidw = &hidL[wave * 16 * 40];

    // ---- depth-1 pipelined j-loop, NO barriers (hidL is per-wave) ----
    const int j00 = jb * 256 + wave * 16;
    float4 ra = *(const float4*)&rightF[(size_t)(j00 + p) * HH + 8 * q];
    float4 rb = *(const float4*)&rightF[(size_t)(j00 + p) * HH + 8 * q + 4];
    int bj = batch[j00 + p], cj = chain[j00 + p], rj = resi[j00 + p], mj = mask[j00 + p];

    #pragma unroll 1
    for (int it = 0; it < 4; ++it) {
        const float4 cra = ra, crb = rb;
        const int cbj = bj, ccj = cj, crj = rj, cmj = mj;
        const int jbase = j00 + it * 64;

        if (it < 3) {   // issue next-iter loads now; first use is next iteration
            const int nj = jbase + 64 + p;
            ra = *(const float4*)&rightF[(size_t)nj * HH + 8 * q];
            rb = *(const float4*)&rightF[(size_t)nj * HH + 8 * q + 4];
            bj = batch[nj]; cj = chain[nj]; rj = resi[nj]; mj = mask[nj];
        }

        const bool sb = (bi == cbj);
        const bool sc = sb && (ci == ccj);
        const float pm = (sb && (mi != 0) && (cmj != 0)) ? 1.0f : 0.0f;

        // ---- build pair vector (A-frag layout: pair p, feats 8q..8q+7) ----
        float pr[8];
        pr[0]=left8[0]+cra.x; pr[1]=left8[1]+cra.y; pr[2]=left8[2]+cra.z; pr[3]=left8[3]+cra.w;
        pr[4]=left8[4]+crb.x; pr[5]=left8[5]+crb.y; pr[6]=left8[6]+crb.z; pr[7]=left8[7]+crb.w;
        if (sc) {
            int d = ri - crj; d = d < -32 ? -32 : (d > 32 ? 32 : d);
            const float4 e0 = *(const float4*)&relL[(d + 32) * 36 + 8 * q];
            const float4 e1 = *(const float4*)&relL[(d + 32) * 36 + 8 * q + 4];
            pr[0]+=e0.x; pr[1]+=e0.y; pr[2]+=e0.z; pr[3]+=e0.w;
            pr[4]+=e1.x; pr[5]+=e1.y; pr[6]+=e1.z; pr[7]+=e1.w;
        }

        // ---- LayerNorm across the 4 quads holding this pair ----
        float s = 0.0f;
        #pragma unroll
        for (int e = 0; e < 8; ++e) s += pr[e];
        s += __shfl_xor(s, 16, 64);
        s += __shfl_xor(s, 32, 64);
        const float mu = s * (1.0f / HH);
        float v = 0.0f;
        #pragma unroll
        for (int e = 0; e < 8; ++e) { float dd = pr[e] - mu; v = fmaf(dd, dd, v); }
        v += __shfl_xor(v, 16, 64);
        v += __shfl_xor(v, 32, 64);
        const float rs = rsqrtf(v * (1.0f / HH) + 1e-5f);

        bf16x8 aF;
        #pragma unroll
        for (int e = 0; e < 8; ++e)
            aF[e] = (short)f2bf(fmaf((pr[e] - mu) * rs, lnS8[e], lnO8[e]));

        // ---- matmul1: hidden = pairLN @ Wh  (two 16-col tiles) ----
        f32x4 z = {0.f, 0.f, 0.f, 0.f};
        f32x4 h0 = __builtin_amdgcn_mfma_f32_16x16x32_bf16(aF, whB0, z, 0, 0, 0);
        f32x4 h1 = __builtin_amdgcn_mfma_f32_16x16x32_bf16(aF, whB1, z, 0, 0, 0);

        // ---- gelu + C->A transform through per-wave LDS (packed b32 writes) ----
        #pragma unroll
        for (int r = 0; r < 4; ++r) {
            const int pr_row = 4 * q + r;     // pair index (C layout row)
            unsigned int pk = (unsigned int)f2bf(gelu_f(h0[r]))
                            | ((unsigned int)f2bf(gelu_f(h1[r])) << 16);
            *(unsigned int*)&hidw[pr_row * 40 + 2 * p] = pk;
        }
        const bf16x8 aH = *(const bf16x8*)&hidw[p * 40 + 8 * q];

        // ---- matmul2: out = hidden @ Wout  (four 16-col tiles, permuted k) ----
        f32x4 o0 = __builtin_amdgcn_mfma_f32_16x16x32_bf16(aH, woB[0], z, 0, 0, 0);
        f32x4 o1 = __builtin_amdgcn_mfma_f32_16x16x32_bf16(aH, woB[1], z, 0, 0, 0);
        f32x4 o2 = __builtin_amdgcn_mfma_f32_16x16x32_bf16(aH, woB[2], z, 0, 0, 0);
        f32x4 o3 = __builtin_amdgcn_mfma_f32_16x16x32_bf16(aH, woB[3], z, 0, 0, 0);

        // ---- mask + store (C layout: row=pair 4q+r, col=16t+p) ----
        float pmv[4];
        #pragma unroll
        for (int r = 0; r < 4; ++r) pmv[r] = __shfl(pm, 4 * q + r, 64);

        #pragma unroll
        for (int r = 0; r < 4; ++r) {
            float* orow = out + ((size_t)i * NN + (size_t)(jbase + 4 * q + r)) * SS + p;
            orow[ 0] = o0[r] * pmv[r];
            orow[16] = o1[r] * pmv[r];
            orow[32] = o2[r] * pmv[r];
            orow[48] = o3[r] * pmv[r];
        }
    }
}

extern "C" void kernel_launch(void* const* d_in, const int* in_sizes, int n_in,
                              void* d_out, int out_size, void* d_ws, size_t ws_size,
                              hipStream_t stream)
{
    const float* local_ = (const float*)d_in[0];
    const int* resi  = (const int*)d_in[1];
    const int* chain = (const int*)d_in[2];
    const int* batch = (const int*)d_in[3];
    const int* mask  = (const int*)d_in[4];
    const float* Wl   = (const float*)d_in[5];
    const float* Wr   = (const float*)d_in[6];
    const float* Wrel = (const float*)d_in[7];
    const float* lnS  = (const float*)d_in[8];
    const float* lnO  = (const float*)d_in[9];
    const float* Wh   = (const float*)d_in[10];
    const float* Wout = (const float*)d_in[11];
    float* out = (float*)d_out;

    float* leftF  = (float*)d_ws;            // 1024*32 fp32
    float* rightF = leftF + NN * HH;         // 1024*32 fp32

    proj_kernel<<<dim3(NN), dim3(64), 0, stream>>>(local_, Wl, Wr, leftF, rightF);
    pair_kernel<<<dim3(4, NN), dim3(256), 0, stream>>>(
        leftF, rightF, resi, chain, batch, mask, Wrel, lnS, lnO, Wh, Wout, out);
}

// Round 5
// 310.797 us; speedup vs baseline: 1.0059x; 1.0059x over previous
//
#include <hip/hip_runtime.h>

#define NN 1024
#define DD 256
#define HH 32
#define SS 64

typedef short bf16x8 __attribute__((ext_vector_type(8)));
typedef float f32x4  __attribute__((ext_vector_type(4)));

__device__ __forceinline__ unsigned short f2bf(float f) {
    union { float f; unsigned int i; } v; v.f = f;
    unsigned int r = v.i + 0x7FFFu + ((v.i >> 16) & 1u);  // RNE; no NaN expected
    return (unsigned short)(r >> 16);
}

__device__ __forceinline__ float gelu_f(float x) {
    // jax.nn.gelu approximate=True
    const float c1 = 0.7978845608028654f, c2 = 0.044715f;
    float u = c1 * fmaf(c2 * x * x, x, x);
    float e = __expf(-2.0f * fabsf(u));
    float th = (1.0f - e) / (1.0f + e);
    th = copysignf(th, u);
    return 0.5f * x * (1.0f + th);
}

// left = local @ W_left, right = local @ W_right  (fp32 out to workspace)
__global__ __launch_bounds__(64) void proj_kernel(
    const float* __restrict__ local_,
    const float* __restrict__ Wl,
    const float* __restrict__ Wr,
    float* __restrict__ leftF, float* __restrict__ rightF)
{
    __shared__ float row[DD];
    const int i = blockIdx.x, t = threadIdx.x;
    float4 v = ((const float4*)(local_ + (size_t)i * DD))[t];
    row[4*t+0] = v.x; row[4*t+1] = v.y; row[4*t+2] = v.z; row[4*t+3] = v.w;
    __syncthreads();
    const int h = t & 31;
    const float* W = (t < 32) ? Wl : Wr;
    float acc = 0.0f;
    #pragma unroll 8
    for (int d = 0; d < DD; ++d) acc = fmaf(row[d], W[d*HH + h], acc);
    float* dst = (t < 32) ? leftF : rightF;
    dst[i*HH + h] = acc;
}

__global__ __launch_bounds__(256) void pair_kernel(
    const float* __restrict__ leftF, const float* __restrict__ rightF,
    const int* __restrict__ resi, const int* __restrict__ chain,
    const int* __restrict__ batch, const int* __restrict__ mask,
    const float* __restrict__ Wrel,
    const float* __restrict__ lnS, const float* __restrict__ lnO,
    const float* __restrict__ Wh, const float* __restrict__ Wout,
    float* __restrict__ out)
{
    __shared__ float relL[65 * 36];              // padded rows: 36 f32 (bank-spread)
    __shared__ unsigned short WhT[32 * 32];      // WhT[n][k] = Wh[k][n], bf16
    __shared__ unsigned short WoT[64 * 32];      // WoT[s'][k'], col+k permuted, bf16
    __shared__ unsigned short hidL[4 * 16 * 40]; // per-wave: 16 pairs x 40-short rows

    const int tid  = threadIdx.x;
    const int wave = tid >> 6;
    const int lane = tid & 63;
    const int q    = lane >> 4;    // quad 0..3
    const int p    = lane & 15;    // pair-slot 0..15
    const int i    = blockIdx.y;
    const int jb   = blockIdx.x;   // 0..3, each covers 256 j

    // ---- one-time staging ----
    for (int idx = tid; idx < 65 * 32; idx += 256)
        relL[(idx >> 5) * 36 + (idx & 31)] = Wrel[idx];
    for (int idx = tid; idx < 32 * 32; idx += 256) {
        int k = idx >> 5, n = idx & 31;
        WhT[n * 32 + k] = f2bf(Wh[idx]);
    }
    for (int idx = tid; idx < 64 * 32; idx += 256) {
        int k2 = idx >> 6, s = idx & 63;         // k2 = permuted feature slot, s = mfma col slot
        int k  = (k2 >> 1) + (k2 & 1) * 16;      // hid slot 2p -> col p, 2p+1 -> col p+16
        int c  = 4 * (s & 15) + (s >> 4);        // mfma tile t, slot p  ->  out col 4p+t
        WoT[s * 32 + k2] = f2bf(Wout[k * SS + c]);
    }
    __syncthreads();

    // ---- block-constant registers ----
    const int bi = batch[i], ci = chain[i], ri = resi[i], mi = mask[i];
    float left8[8], lnS8[8], lnO8[8];
    {
        const float4 l0 = *(const float4*)&leftF[i * HH + 8 * q];
        const float4 l1 = *(const float4*)&leftF[i * HH + 8 * q + 4];
        left8[0]=l0.x; left8[1]=l0.y; left8[2]=l0.z; left8[3]=l0.w;
        left8[4]=l1.x; left8[5]=l1.y; left8[6]=l1.z; left8[7]=l1.w;
        #pragma unroll
        for (int e = 0; e < 8; ++e) { lnS8[e] = lnS[8*q + e]; lnO8[e] = lnO[8*q + e]; }
    }
    const bf16x8 whB0 = *(const bf16x8*)&WhT[(p      ) * 32 + 8 * q];
    const bf16x8 whB1 = *(const bf16x8*)&WhT[(16 + p ) * 32 + 8 * q];
    bf16x8 woB[4];
    #pragma unroll
    for (int t = 0; t < 4; ++t)
        woB[t] = *(const bf16x8*)&WoT[(16 * t + p) * 32 + 8 * q];

    unsigned short* hidw = &hidL[wave * 16 * 40];

    // ---- depth-1 pipelined j-loop, NO barriers (hidL is per-wave) ----
    const int j00 = jb * 256 + wave * 16;
    float4 ra = *(const float4*)&rightF[(size_t)(j00 + p) * HH + 8 * q];
    float4 rb = *(const float4*)&rightF[(size_t)(j00 + p) * HH + 8 * q + 4];
    int bj = batch[j00 + p], cj = chain[j00 + p], rj = resi[j00 + p], mj = mask[j00 + p];

    #pragma unroll 1
    for (int it = 0; it < 4; ++it) {
        const float4 cra = ra, crb = rb;
        const int cbj = bj, ccj = cj, crj = rj, cmj = mj;
        const int jbase = j00 + it * 64;

        if (it < 3) {   // issue next-iter loads now; first use is next iteration
            const int nj = jbase + 64 + p;
            ra = *(const float4*)&rightF[(size_t)nj * HH + 8 * q];
            rb = *(const float4*)&rightF[(size_t)nj * HH + 8 * q + 4];
            bj = batch[nj]; cj = chain[nj]; rj = resi[nj]; mj = mask[nj];
        }

        const bool sb = (bi == cbj);
        const bool sc = sb && (ci == ccj);
        const float pm = (sb && (mi != 0) && (cmj != 0)) ? 1.0f : 0.0f;

        // ---- build pair vector (A-frag layout: pair p, feats 8q..8q+7) ----
        float pr[8];
        pr[0]=left8[0]+cra.x; pr[1]=left8[1]+cra.y; pr[2]=left8[2]+cra.z; pr[3]=left8[3]+cra.w;
        pr[4]=left8[4]+crb.x; pr[5]=left8[5]+crb.y; pr[6]=left8[6]+crb.z; pr[7]=left8[7]+crb.w;
        if (sc) {
            int d = ri - crj; d = d < -32 ? -32 : (d > 32 ? 32 : d);
            const float4 e0 = *(const float4*)&relL[(d + 32) * 36 + 8 * q];
            const float4 e1 = *(const float4*)&relL[(d + 32) * 36 + 8 * q + 4];
            pr[0]+=e0.x; pr[1]+=e0.y; pr[2]+=e0.z; pr[3]+=e0.w;
            pr[4]+=e1.x; pr[5]+=e1.y; pr[6]+=e1.z; pr[7]+=e1.w;
        }

        // ---- LayerNorm across the 4 quads holding this pair ----
        float s = 0.0f;
        #pragma unroll
        for (int e = 0; e < 8; ++e) s += pr[e];
        s += __shfl_xor(s, 16, 64);
        s += __shfl_xor(s, 32, 64);
        const float mu = s * (1.0f / HH);
        float v = 0.0f;
        #pragma unroll
        for (int e = 0; e < 8; ++e) { float dd = pr[e] - mu; v = fmaf(dd, dd, v); }
        v += __shfl_xor(v, 16, 64);
        v += __shfl_xor(v, 32, 64);
        const float rs = rsqrtf(v * (1.0f / HH) + 1e-5f);

        bf16x8 aF;
        #pragma unroll
        for (int e = 0; e < 8; ++e)
            aF[e] = (short)f2bf(fmaf((pr[e] - mu) * rs, lnS8[e], lnO8[e]));

        // ---- matmul1: hidden = pairLN @ Wh  (two 16-col tiles) ----
        f32x4 z = {0.f, 0.f, 0.f, 0.f};
        f32x4 h0 = __builtin_amdgcn_mfma_f32_16x16x32_bf16(aF, whB0, z, 0, 0, 0);
        f32x4 h1 = __builtin_amdgcn_mfma_f32_16x16x32_bf16(aF, whB1, z, 0, 0, 0);

        // ---- gelu + C->A transform through per-wave LDS (packed b32 writes) ----
        #pragma unroll
        for (int r = 0; r < 4; ++r) {
            const int pr_row = 4 * q + r;     // pair index (C layout row)
            unsigned int pk = (unsigned int)f2bf(gelu_f(h0[r]))
                            | ((unsigned int)f2bf(gelu_f(h1[r])) << 16);
            *(unsigned int*)&hidw[pr_row * 40 + 2 * p] = pk;
        }
        const bf16x8 aH = *(const bf16x8*)&hidw[p * 40 + 8 * q];

        // ---- matmul2: out = hidden @ Wout  (4 tiles; tile t slot p = out col 4p+t) ----
        f32x4 o0 = __builtin_amdgcn_mfma_f32_16x16x32_bf16(aH, woB[0], z, 0, 0, 0);
        f32x4 o1 = __builtin_amdgcn_mfma_f32_16x16x32_bf16(aH, woB[1], z, 0, 0, 0);
        f32x4 o2 = __builtin_amdgcn_mfma_f32_16x16x32_bf16(aH, woB[2], z, 0, 0, 0);
        f32x4 o3 = __builtin_amdgcn_mfma_f32_16x16x32_bf16(aH, woB[3], z, 0, 0, 0);

        // ---- mask + store: lane (q,p) owns rows 4q+r, cols 4p..4p+3 -> float4 ----
        float pmv[4];
        #pragma unroll
        for (int r = 0; r < 4; ++r) pmv[r] = __shfl(pm, 4 * q + r, 64);

        #pragma unroll
        for (int r = 0; r < 4; ++r) {
            const float m = pmv[r];
            float4 vv = make_float4(o0[r] * m, o1[r] * m, o2[r] * m, o3[r] * m);
            *(float4*)(out + ((size_t)i * NN + (size_t)(jbase + 4 * q + r)) * SS + 4 * p) = vv;
        }
    }
}

extern "C" void kernel_launch(void* const* d_in, const int* in_sizes, int n_in,
                              void* d_out, int out_size, void* d_ws, size_t ws_size,
                              hipStream_t stream)
{
    const float* local_ = (const float*)d_in[0];
    const int* resi  = (const int*)d_in[1];
    const int* chain = (const int*)d_in[2];
    const int* batch = (const int*)d_in[3];
    const int* mask  = (const int*)d_in[4];
    const float* Wl   = (const float*)d_in[5];
    const float* Wr   = (const float*)d_in[6];
    const float* Wrel = (const float*)d_in[7];
    const float* lnS  = (const float*)d_in[8];
    const float* lnO  = (const float*)d_in[9];
    const float* Wh   = (const float*)d_in[10];
    const float* Wout = (const float*)d_in[11];
    float* out = (float*)d_out;

    float* leftF  = (float*)d_ws;            // 1024*32 fp32
    float* rightF = leftF + NN * HH;         // 1024*32 fp32

    proj_kernel<<<dim3(NN), dim3(64), 0, stream>>>(local_, Wl, Wr, leftF, rightF);
    pair_kernel<<<dim3(4, NN), dim3(256), 0, stream>>>(
        leftF, rightF, resi, chain, batch, mask, Wrel, lnS, lnO, Wh, Wout, out);
}

// Round 6
// 307.571 us; speedup vs baseline: 1.0164x; 1.0105x over previous
//
#include <hip/hip_runtime.h>

#define NN 1024
#define DD 256
#define HH 32
#define SS 64

typedef short bf16x8 __attribute__((ext_vector_type(8)));
typedef float f32x4  __attribute__((ext_vector_type(4)));

__device__ __forceinline__ unsigned short f2bf(float f) {
    union { float f; unsigned int i; } v; v.f = f;
    unsigned int r = v.i + 0x7FFFu + ((v.i >> 16) & 1u);  // RNE; no NaN expected
    return (unsigned short)(r >> 16);
}
__device__ __forceinline__ float bflo(unsigned int pk) {   // low bf16 -> f32
    union { unsigned int i; float f; } v; v.i = pk << 16; return v.f;
}
__device__ __forceinline__ float bfhi(unsigned int pk) {   // high bf16 -> f32
    union { unsigned int i; float f; } v; v.i = pk & 0xFFFF0000u; return v.f;
}

__device__ __forceinline__ float gelu_f(float x) {
    // jax.nn.gelu approximate=True
    const float c1 = 0.7978845608028654f, c2 = 0.044715f;
    float u = c1 * fmaf(c2 * x * x, x, x);
    float e = __expf(-2.0f * fabsf(u));
    float th = (1.0f - e) / (1.0f + e);
    th = copysignf(th, u);
    return 0.5f * x * (1.0f + th);
}

// left = local @ W_left, right = local @ W_right  (fp32 out to workspace)
__global__ __launch_bounds__(64) void proj_kernel(
    const float* __restrict__ local_,
    const float* __restrict__ Wl,
    const float* __restrict__ Wr,
    float* __restrict__ leftF, float* __restrict__ rightF)
{
    __shared__ float row[DD];
    const int i = blockIdx.x, t = threadIdx.x;
    float4 v = ((const float4*)(local_ + (size_t)i * DD))[t];
    row[4*t+0] = v.x; row[4*t+1] = v.y; row[4*t+2] = v.z; row[4*t+3] = v.w;
    __syncthreads();
    const int h = t & 31;
    const float* W = (t < 32) ? Wl : Wr;
    float acc = 0.0f;
    #pragma unroll 8
    for (int d = 0; d < DD; ++d) acc = fmaf(row[d], W[d*HH + h], acc);
    float* dst = (t < 32) ? leftF : rightF;
    dst[i*HH + h] = acc;
}

// meta[j] = {resi, chain, batch, mask}
__global__ __launch_bounds__(256) void pack_meta(
    const int* __restrict__ resi, const int* __restrict__ chain,
    const int* __restrict__ batch, const int* __restrict__ mask,
    int4* __restrict__ meta)
{
    const int j = blockIdx.x * 256 + threadIdx.x;
    meta[j] = make_int4(resi[j], chain[j], batch[j], mask[j]);
}

__global__ __launch_bounds__(256, 4) void pair_kernel(
    const float* __restrict__ leftF, const float* __restrict__ rightF,
    const int4* __restrict__ metaJ,
    const float* __restrict__ Wrel,
    const float* __restrict__ lnS, const float* __restrict__ lnO,
    const float* __restrict__ Wh, const float* __restrict__ Wout,
    float* __restrict__ out)
{
    __shared__ unsigned short relL[65 * 40];     // bf16, 40-short rows (80 B, 16B-aligned)
    __shared__ unsigned short WhT[32 * 32];      // WhT[n][k] = Wh[k][n], bf16
    __shared__ unsigned short WoT[64 * 32];      // col+k permuted, bf16
    __shared__ unsigned short hidL[4 * 16 * 40]; // per-wave: 16 pairs x 40-short rows

    const int tid  = threadIdx.x;
    const int wave = tid >> 6;
    const int lane = tid & 63;
    const int q    = lane >> 4;    // quad 0..3
    const int p    = lane & 15;    // pair-slot 0..15
    const int i    = blockIdx.y;
    const int jb   = blockIdx.x;   // 0..1, each covers 512 j

    // ---- one-time staging ----
    for (int idx = tid; idx < 65 * 32; idx += 256)
        relL[(idx >> 5) * 40 + (idx & 31)] = f2bf(Wrel[idx]);
    for (int idx = tid; idx < 32 * 32; idx += 256) {
        int k = idx >> 5, n = idx & 31;
        WhT[n * 32 + k] = f2bf(Wh[idx]);
    }
    for (int idx = tid; idx < 64 * 32; idx += 256) {
        int k2 = idx >> 6, s = idx & 63;         // k2 = permuted feature slot, s = mfma col slot
        int k  = (k2 >> 1) + (k2 & 1) * 16;      // hid slot 2p -> col p, 2p+1 -> col p+16
        int c  = 4 * (s & 15) + (s >> 4);        // mfma tile t, slot p  ->  out col 4p+t
        WoT[s * 32 + k2] = f2bf(Wout[k * SS + c]);
    }
    __syncthreads();

    // ---- block-constant registers ----
    const int4 mti = metaJ[i];
    const int ri = mti.x, ci = mti.y, bi = mti.z, mi = mti.w;
    float left8[8], lnS8[8], lnO8[8];
    {
        const float4 l0 = *(const float4*)&leftF[i * HH + 8 * q];
        const float4 l1 = *(const float4*)&leftF[i * HH + 8 * q + 4];
        left8[0]=l0.x; left8[1]=l0.y; left8[2]=l0.z; left8[3]=l0.w;
        left8[4]=l1.x; left8[5]=l1.y; left8[6]=l1.z; left8[7]=l1.w;
        #pragma unroll
        for (int e = 0; e < 8; ++e) { lnS8[e] = lnS[8*q + e]; lnO8[e] = lnO[8*q + e]; }
    }
    const bf16x8 whB0 = *(const bf16x8*)&WhT[(p      ) * 32 + 8 * q];
    const bf16x8 whB1 = *(const bf16x8*)&WhT[(16 + p ) * 32 + 8 * q];
    bf16x8 woB[4];
    #pragma unroll
    for (int t = 0; t < 4; ++t)
        woB[t] = *(const bf16x8*)&WoT[(16 * t + p) * 32 + 8 * q];

    unsigned short* hidw = &hidL[wave * 16 * 40];

    // ---- depth-1 pipelined j-loop, NO barriers (hidL is per-wave) ----
    const int j00 = jb * 512 + wave * 16;
    float4 ra = *(const float4*)&rightF[(size_t)(j00 + p) * HH + 8 * q];
    float4 rb = *(const float4*)&rightF[(size_t)(j00 + p) * HH + 8 * q + 4];
    int4 mt = metaJ[j00 + p];

    #pragma unroll 1
    for (int it = 0; it < 8; ++it) {
        const float4 cra = ra, crb = rb;
        const int4 cmt = mt;
        const int jbase = j00 + it * 64;

        if (it < 7) {   // issue next-iter loads now; first use is next iteration
            const int nj = jbase + 64 + p;
            ra = *(const float4*)&rightF[(size_t)nj * HH + 8 * q];
            rb = *(const float4*)&rightF[(size_t)nj * HH + 8 * q + 4];
            mt = metaJ[nj];
        }

        const bool sb = (bi == cmt.z);
        const bool sc = sb && (ci == cmt.y);
        const float pm = (sb && (mi != 0) && (cmt.w != 0)) ? 1.0f : 0.0f;

        // ---- build pair vector (A-frag layout: pair p, feats 8q..8q+7) ----
        float pr[8];
        pr[0]=left8[0]+cra.x; pr[1]=left8[1]+cra.y; pr[2]=left8[2]+cra.z; pr[3]=left8[3]+cra.w;
        pr[4]=left8[4]+crb.x; pr[5]=left8[5]+crb.y; pr[6]=left8[6]+crb.z; pr[7]=left8[7]+crb.w;
        if (sc) {
            int d = ri - cmt.x; d = d < -32 ? -32 : (d > 32 ? 32 : d);
            const uint4 e4 = *(const uint4*)&relL[(d + 32) * 40 + 8 * q];
            pr[0]+=bflo(e4.x); pr[1]+=bfhi(e4.x); pr[2]+=bflo(e4.y); pr[3]+=bfhi(e4.y);
            pr[4]+=bflo(e4.z); pr[5]+=bfhi(e4.z); pr[6]+=bflo(e4.w); pr[7]+=bfhi(e4.w);
        }

        // ---- LayerNorm: interleaved sum / sum-of-squares reductions ----
        float s = 0.0f, s2 = 0.0f;
        #pragma unroll
        for (int e = 0; e < 8; ++e) { s += pr[e]; s2 = fmaf(pr[e], pr[e], s2); }
        s  += __shfl_xor(s, 16, 64);
        s2 += __shfl_xor(s2, 16, 64);
        s  += __shfl_xor(s, 32, 64);
        s2 += __shfl_xor(s2, 32, 64);
        const float mu  = s * (1.0f / HH);
        const float var = fmaf(-mu, mu, s2 * (1.0f / HH));
        const float rs  = rsqrtf(var + 1e-5f);

        bf16x8 aF;
        #pragma unroll
        for (int e = 0; e < 8; ++e)
            aF[e] = (short)f2bf(fmaf((pr[e] - mu) * rs, lnS8[e], lnO8[e]));

        // ---- matmul1: hidden = pairLN @ Wh  (two 16-col tiles) ----
        f32x4 z = {0.f, 0.f, 0.f, 0.f};
        f32x4 h0 = __builtin_amdgcn_mfma_f32_16x16x32_bf16(aF, whB0, z, 0, 0, 0);
        f32x4 h1 = __builtin_amdgcn_mfma_f32_16x16x32_bf16(aF, whB1, z, 0, 0, 0);

        // ---- gelu + C->A transform through per-wave LDS (packed b32 writes) ----
        #pragma unroll
        for (int r = 0; r < 4; ++r) {
            const int pr_row = 4 * q + r;     // pair index (C layout row)
            unsigned int pk = (unsigned int)f2bf(gelu_f(h0[r]))
                            | ((unsigned int)f2bf(gelu_f(h1[r])) << 16);
            *(unsigned int*)&hidw[pr_row * 40 + 2 * p] = pk;
        }
        const bf16x8 aH = *(const bf16x8*)&hidw[p * 40 + 8 * q];

        // ---- matmul2: out = hidden @ Wout  (4 tiles; tile t slot p = out col 4p+t) ----
        f32x4 o0 = __builtin_amdgcn_mfma_f32_16x16x32_bf16(aH, woB[0], z, 0, 0, 0);
        f32x4 o1 = __builtin_amdgcn_mfma_f32_16x16x32_bf16(aH, woB[1], z, 0, 0, 0);
        f32x4 o2 = __builtin_amdgcn_mfma_f32_16x16x32_bf16(aH, woB[2], z, 0, 0, 0);
        f32x4 o3 = __builtin_amdgcn_mfma_f32_16x16x32_bf16(aH, woB[3], z, 0, 0, 0);

        // ---- mask + store: lane (q,p) owns rows 4q+r, cols 4p..4p+3 -> float4 ----
        float pmv[4];
        #pragma unroll
        for (int r = 0; r < 4; ++r) pmv[r] = __shfl(pm, 4 * q + r, 64);

        #pragma unroll
        for (int r = 0; r < 4; ++r) {
            const float m = pmv[r];
            float4 vv = make_float4(o0[r] * m, o1[r] * m, o2[r] * m, o3[r] * m);
            *(float4*)(out + ((size_t)i * NN + (size_t)(jbase + 4 * q + r)) * SS + 4 * p) = vv;
        }
    }
}

extern "C" void kernel_launch(void* const* d_in, const int* in_sizes, int n_in,
                              void* d_out, int out_size, void* d_ws, size_t ws_size,
                              hipStream_t stream)
{
    const float* local_ = (const float*)d_in[0];
    const int* resi  = (const int*)d_in[1];
    const int* chain = (const int*)d_in[2];
    const int* batch = (const int*)d_in[3];
    const int* mask  = (const int*)d_in[4];
    const float* Wl   = (const float*)d_in[5];
    const float* Wr   = (const float*)d_in[6];
    const float* Wrel = (const float*)d_in[7];
    const float* lnS  = (const float*)d_in[8];
    const float* lnO  = (const float*)d_in[9];
    const float* Wh   = (const float*)d_in[10];
    const float* Wout = (const float*)d_in[11];
    float* out = (float*)d_out;

    float* leftF  = (float*)d_ws;                    // 1024*32 fp32
    float* rightF = leftF + NN * HH;                 // 1024*32 fp32
    int4*  metaJ  = (int4*)(rightF + NN * HH);       // 1024 int4 (16B-aligned)

    proj_kernel<<<dim3(NN), dim3(64), 0, stream>>>(local_, Wl, Wr, leftF, rightF);
    pack_meta<<<dim3(NN / 256), dim3(256), 0, stream>>>(resi, chain, batch, mask, metaJ);
    pair_kernel<<<dim3(2, NN), dim3(256), 0, stream>>>(
        leftF, rightF, metaJ, Wrel, lnS, lnO, Wh, Wout, out);
}